// Round 6
// baseline (729.375 us; speedup 1.0000x reference)
//
#include <hip/hip_runtime.h>

#define N 8192
#define D 1024

typedef short bf16x8 __attribute__((ext_vector_type(8)));
typedef float f32x4 __attribute__((ext_vector_type(4)));
typedef unsigned short u16;

#define WAITV(n) asm volatile("s_waitcnt vmcnt(" #n ")" ::: "memory")
#define BAR() __builtin_amdgcn_s_barrier()

__device__ __forceinline__ u16 f2bf(float f) {
  unsigned u = __float_as_uint(f);
  u += 0x7FFF + ((u >> 16) & 1);   // RNE to bf16
  return (u16)(u >> 16);
}
__device__ __forceinline__ float bf2f(u16 h) {
  return __uint_as_float(((unsigned)h) << 16);
}

__device__ __forceinline__ void gload_lds16(const void* g, const void* l) {
  __builtin_amdgcn_global_load_lds(
      (const __attribute__((address_space(1))) void*)g,
      (__attribute__((address_space(3))) void*)l, 16, 0, 0);
}

// Swizzled [rows][32] bf16 tile, 64 B/row, 4x 16B chunks per row.
// Physical chunk = logical chunk ^ ((row>>1)&3). Involution applied on both
// the stage (global-source side) and the ds_read side.
__device__ __forceinline__ int swz_byte(int row, int logical_chunk) {
  return row * 64 + ((logical_chunk ^ ((row >> 1) & 3)) << 4);
}

// ---------------- K0: split X (fp32) into Hi/Lo bf16 ----------------
__global__ __launch_bounds__(256) void k_split(const float* __restrict__ X,
                                               u16* __restrict__ hi,
                                               u16* __restrict__ lo) {
  int i = blockIdx.x * 256 + threadIdx.x;   // float4 index, total N*D/4
  float4 x = ((const float4*)X)[i];
  u16 h0 = f2bf(x.x), h1 = f2bf(x.y), h2 = f2bf(x.z), h3 = f2bf(x.w);
  ushort4 hv = {h0, h1, h2, h3};
  ushort4 lv = {f2bf(x.x - bf2f(h0)), f2bf(x.y - bf2f(h1)),
                f2bf(x.z - bf2f(h2)), f2bf(x.w - bf2f(h3))};
  ((ushort4*)hi)[i] = hv;
  ((ushort4*)lo)[i] = lv;
}

// ---------------- K0b: transpose Xhi [N][D] -> XT [D][N] ----------------
__global__ __launch_bounds__(256) void k_transpose(const u16* __restrict__ Xh,
                                                   u16* __restrict__ XT) {
  __shared__ u16 t[32][33];
  const int jt = blockIdx.y * 32, dt = blockIdx.x * 32;
  const int c = threadIdx.x & 31, rg = threadIdx.x >> 5;   // rg in 0..7
#pragma unroll
  for (int k = 0; k < 4; ++k) {
    int r = rg * 4 + k;
    t[r][c] = Xh[(size_t)(jt + r) * D + dt + c];
  }
  __syncthreads();
#pragma unroll
  for (int k = 0; k < 4; ++k) {
    int d = rg * 4 + k;
    XT[(size_t)(dt + d) * N + jt + c] = t[c][d];
  }
}

// ------- K1: S = X X^T, symmetric, 256x256 blocks, 8 waves ------------
// Wave tile 128x64 (fewer LDS bytes per MFMA FLOP than 64x64).
// Serialized stage->sync->compute (R4: DMA/ds_read overlap = conflict storm).
__global__ __launch_bounds__(512, 2) void k_qkt(const u16* __restrict__ Xh,
                                                const u16* __restrict__ Xl,
                                                float* __restrict__ S) {
  __shared__ union {
    u16 stage[4][256 * 32];     // Ah, Al, Bh, Bl (64 KiB)
    float tbuf[64][256];        // transpose bounce (64 KiB, XOR-swizzled)
  } sm;

  const int tid = threadIdx.x, wid = tid >> 6, lane = tid & 63;

  // XCD chunk swizzle over 528 blocks (528 = 8 * 66, bijective)
  int o = blockIdx.x;
  int l = (o & 7) * 66 + (o >> 3);
  // map linear id -> (bi, bj), bi <= bj, over 32x32 block grid
  int t = l, bi = 0;
  while (t >= 32 - bi) { t -= 32 - bi; ++bi; }
  const int bj = bi + t;
  const int brow = bi * 256, bcol = bj * 256;

  const int wr = wid >> 2, wc = wid & 3;   // 2x4 waves; wave tile 128x64
  const int fr = lane & 15;
  const int c0 = lane >> 4;                // logical 16B chunk for ds_read

  // stage role of this wave: tile 0=Ah 1=Al 2=Bh 3=Bl; 2 waves per tile
  const int stile = wid >> 1;
  const u16* xsrc = (stile & 1) ? Xl : Xh;
  const int rbase = (stile >> 1) ? bcol : brow;

  f32x4 acc[8][4] = {};

  for (int kt = 0; kt < D; kt += 32) {
    __syncthreads();
    // stage 4 tiles (256x32 bf16 each = 16 KiB); 8 chunks of 1 KiB per wave
#pragma unroll
    for (int c = 0; c < 8; ++c) {
      int sub = (wid & 1) * 8 + c;           // 0..15 within tile
      int ebyte = sub * 1024 + lane * 16;    // linear LDS dest byte
      int row = ebyte >> 6;
      int pc = (ebyte >> 4) & 3;             // physical chunk slot
      int col = (pc ^ ((row >> 1) & 3)) * 8; // logical col staged there
      gload_lds16(xsrc + (size_t)(rbase + row) * D + kt + col,
                  (const char*)sm.stage[stile] + ebyte);
    }
    __syncthreads();

    bf16x8 bh[4], bl[4];
#pragma unroll
    for (int n = 0; n < 4; ++n) {
      int row = wc * 64 + n * 16 + fr;
      int pb = swz_byte(row, c0);
      bh[n] = *(const bf16x8*)((const char*)sm.stage[2] + pb);
      bl[n] = *(const bf16x8*)((const char*)sm.stage[3] + pb);
    }
#pragma unroll
    for (int m = 0; m < 8; ++m) {
      int row = wr * 128 + m * 16 + fr;
      int pb = swz_byte(row, c0);
      bf16x8 ahm = *(const bf16x8*)((const char*)sm.stage[0] + pb);
      bf16x8 alm = *(const bf16x8*)((const char*)sm.stage[1] + pb);
#pragma unroll
      for (int n = 0; n < 4; ++n) {
        acc[m][n] = __builtin_amdgcn_mfma_f32_16x16x32_bf16(ahm, bh[n], acc[m][n], 0, 0, 0);
        acc[m][n] = __builtin_amdgcn_mfma_f32_16x16x32_bf16(ahm, bl[n], acc[m][n], 0, 0, 0);
        acc[m][n] = __builtin_amdgcn_mfma_f32_16x16x32_bf16(alm, bh[n], acc[m][n], 0, 0, 0);
      }
    }
  }

  const int rr = (lane >> 4) * 4;
  // direct tile write: S[brow..][bcol..]
#pragma unroll
  for (int m = 0; m < 8; ++m)
#pragma unroll
    for (int n = 0; n < 4; ++n)
#pragma unroll
      for (int r = 0; r < 4; ++r) {
        int row = brow + wr * 128 + m * 16 + rr + r;
        int col = bcol + wc * 64 + n * 16 + fr;
        S[(size_t)row * N + col] = acc[m][n][r];
      }

  // transposed tile write for off-diagonal blocks: S[bcol..][brow..]
  // 4 passes of 64 columns; tbuf[c][row] with XOR-swizzled inner bytes.
  if (bi != bj) {
#pragma unroll
    for (int pass = 0; pass < 4; ++pass) {
      __syncthreads();                 // stage/tbuf reuse + prior reads done
      if (wc == pass) {
#pragma unroll
        for (int m = 0; m < 8; ++m)
#pragma unroll
          for (int n = 0; n < 4; ++n) {
            f32x4 v = acc[m][n];
            int c = n * 16 + fr;                     // 0..63
            int rl = wr * 128 + m * 16 + rr;         // 0..255 (quad base)
            int inner = (rl * 4) ^ ((c & 15) << 4);
            *(f32x4*)((char*)&sm.tbuf[c][0] + inner) = v;
          }
      }
      __syncthreads();
#pragma unroll
      for (int i = 0; i < 8; ++i) {
        int idx = i * 512 + tid;         // 4096 float4 = 64 cols x 64 quads
        int c = idx >> 6;                // 0..63
        int rq = idx & 63;               // 0..63 (row quad)
        int inner = (rq * 16) ^ ((c & 15) << 4);
        float4 v4 = *(const float4*)((const char*)&sm.tbuf[c][0] + inner);
        *(float4*)&S[(size_t)(bcol + pass * 64 + c) * N + brow + rq * 4] = v4;
      }
    }
  }
}

// ---------------- K2: in-place row softmax (+ optional bf16 P copy) -----
template <int WRITE_PB>
__global__ __launch_bounds__(256) void k_softmax(float* __restrict__ S,
                                                 u16* __restrict__ Pb) {
  const int row = blockIdx.x;
  float* p = S + (size_t)row * N;
  const int tid = threadIdx.x;
  const int wid = tid >> 6, lane = tid & 63;
  __shared__ float red[4];

  float4 v[8];
  float m = -INFINITY;
#pragma unroll
  for (int i = 0; i < 8; ++i) {
    int idx = i * 256 + tid;              // float4 index within row
    float4 x = ((const float4*)p)[idx];
    if ((row >> 2) == idx) ((float*)&x)[row & 3] = -INFINITY;  // exclude diag
    v[i] = x;
    m = fmaxf(m, fmaxf(fmaxf(x.x, x.y), fmaxf(x.z, x.w)));
  }
#pragma unroll
  for (int off = 32; off > 0; off >>= 1) m = fmaxf(m, __shfl_xor(m, off));
  if (lane == 0) red[wid] = m;
  __syncthreads();
  m = fmaxf(fmaxf(red[0], red[1]), fmaxf(red[2], red[3]));

  float s = 0.f;
#pragma unroll
  for (int i = 0; i < 8; ++i) {
    float4 e;
    e.x = __expf(v[i].x - m);
    e.y = __expf(v[i].y - m);
    e.z = __expf(v[i].z - m);
    e.w = __expf(v[i].w - m);
    v[i] = e;
    s += e.x + e.y + e.z + e.w;
  }
#pragma unroll
  for (int off = 32; off > 0; off >>= 1) s += __shfl_xor(s, off);
  __syncthreads();                        // red[] reuse
  if (lane == 0) red[wid] = s;
  __syncthreads();
  s = red[0] + red[1] + red[2] + red[3];
  float inv = 1.0f / s;
#pragma unroll
  for (int i = 0; i < 8; ++i) {
    int idx = i * 256 + tid;
    float4 x = v[i];
    x.x *= inv; x.y *= inv; x.z *= inv; x.w *= inv;
    ((float4*)p)[idx] = x;
    if (WRITE_PB) {
      ushort4 h = {f2bf(x.x), f2bf(x.y), f2bf(x.z), f2bf(x.w)};
      ((ushort4*)(Pb + (size_t)row * N))[idx] = h;
    }
  }
}

// -------- K3: out = P @ X, bf16 Pb path. BM=BN=128, 256 thr -------------
// 4-deep global_load_lds pipeline (4 loads/wave/stage), counted vmcnt,
// raw barriers; 512 blocks = 2/CU for TLP + fetch streams.
__global__ __launch_bounds__(256) void k_pv(const u16* __restrict__ Pb,
                                            const u16* __restrict__ XT,
                                            float* __restrict__ Out) {
  __shared__ u16 As[4][128 * 32];   // 32 KiB
  __shared__ u16 Bs[4][128 * 32];   // 32 KiB
  const int tid = threadIdx.x, wid = tid >> 6, lane = tid & 63;

  // XCD chunk swizzle over 512 blocks (q=64, bijective); the 8 bcol-blocks
  // of a Pb row-panel stay adjacent within an XCD band.
  int o = blockIdx.x;
  int l = (o & 7) * 64 + (o >> 3);
  const int brow = (l >> 3) * 128;     // rows of P / out
  const int bcol = (l & 7) * 128;      // cols of out (d)

  const int wr = wid >> 1, wc = wid & 1;   // 2x2 waves, 64x64 each
  const int fr = lane & 15;
  const int c0 = lane >> 4;

  // stage role: waves 0,1 -> A (Pb), waves 2,3 -> B (XT)
  const bool isA = wid < 2;

  f32x4 acc[4][4] = {};

#define PV_STAGE(kt, s) do {                                               \
    _Pragma("unroll")                                                      \
    for (int c = 0; c < 4; ++c) {                                          \
      int sub = (wid & 1) * 4 + c;           /* 0..7 within tile */        \
      int ebyte = sub * 1024 + lane * 16;                                  \
      int row = ebyte >> 6;                                                \
      int pc = (ebyte >> 4) & 3;                                           \
      int col = (pc ^ ((row >> 1) & 3)) * 8;                               \
      const u16* src = isA ? Pb + (size_t)(brow + row) * N + (kt) + col    \
                           : XT + (size_t)(bcol + row) * N + (kt) + col;   \
      gload_lds16(src, (const char*)(isA ? As[s] : Bs[s]) + ebyte);        \
    }                                                                      \
  } while (0)

#define PV_COMPUTE(s) do {                                                 \
    bf16x8 a[4], b[4];                                                     \
    _Pragma("unroll")                                                      \
    for (int m = 0; m < 4; ++m) {                                          \
      int row = wr * 64 + m * 16 + fr;                                     \
      a[m] = *(const bf16x8*)((const char*)As[s] + swz_byte(row, c0));     \
    }                                                                      \
    _Pragma("unroll")                                                      \
    for (int n = 0; n < 4; ++n) {                                          \
      int row = wc * 64 + n * 16 + fr;                                     \
      b[n] = *(const bf16x8*)((const char*)Bs[s] + swz_byte(row, c0));     \
    }                                                                      \
    _Pragma("unroll")                                                      \
    for (int m = 0; m < 4; ++m)                                            \
      _Pragma("unroll")                                                    \
      for (int n = 0; n < 4; ++n)                                          \
        acc[m][n] = __builtin_amdgcn_mfma_f32_16x16x32_bf16(a[m], b[n], acc[m][n], 0, 0, 0); \
  } while (0)

  PV_STAGE(0, 0);
  PV_STAGE(32, 1);
  PV_STAGE(64, 2);
  PV_STAGE(96, 3);
  int s = 0;
  for (int it = 0; it < 252; ++it) {
    WAITV(12);                   // tile it's 4 loads done; 12 in flight
    BAR();
    PV_COMPUTE(s);
    asm volatile("s_waitcnt lgkmcnt(0)" ::: "memory");
    BAR();
    PV_STAGE((it + 4) * 32, s);
    s = (s + 1) & 3;
  }
  // tail: tiles 252..255, nothing new issued
  WAITV(12); BAR(); PV_COMPUTE(s);
  asm volatile("s_waitcnt lgkmcnt(0)" ::: "memory"); BAR(); s = (s + 1) & 3;
  WAITV(8);  BAR(); PV_COMPUTE(s);
  asm volatile("s_waitcnt lgkmcnt(0)" ::: "memory"); BAR(); s = (s + 1) & 3;
  WAITV(4);  BAR(); PV_COMPUTE(s);
  asm volatile("s_waitcnt lgkmcnt(0)" ::: "memory"); BAR(); s = (s + 1) & 3;
  WAITV(0);  BAR(); PV_COMPUTE(s);

#undef PV_STAGE
#undef PV_COMPUTE

  const int rr = (lane >> 4) * 4;
#pragma unroll
  for (int m = 0; m < 4; ++m)
#pragma unroll
    for (int n = 0; n < 4; ++n)
#pragma unroll
      for (int r = 0; r < 4; ++r) {
        int row = brow + wr * 64 + m * 16 + rr + r;
        int col = bcol + wc * 64 + n * 16 + fr;
        Out[(size_t)row * D + col] = acc[m][n][r];
      }
}

// -------- K3 fallback: out = P @ X from fp32 P (no Pb workspace) --------
__global__ __launch_bounds__(512) void k_pv_f32(const float* __restrict__ P,
                                                const u16* __restrict__ XT,
                                                float* __restrict__ Out) {
  __shared__ u16 As[128 * 32];
  __shared__ u16 Bs[256 * 32];
  const int tid = threadIdx.x, wid = tid >> 6, lane = tid & 63;
  const int brow = blockIdx.y * 128;
  const int bcol = blockIdx.x * 256;
  const int wr = wid >> 2, wc = wid & 3;
  const int fr = lane & 15;
  const int c0 = lane >> 4;

  f32x4 acc[4][4] = {};

  for (int kt = 0; kt < N; kt += 32) {
    __syncthreads();
#pragma unroll
    for (int c = 0; c < 2; ++c) {
      int chunk = wid * 2 + c;
      int ebyte = chunk * 1024 + lane * 16;
      int row = ebyte >> 6;
      int pc = (ebyte >> 4) & 3;
      int col = (pc ^ ((row >> 1) & 3)) * 8;
      gload_lds16(XT + (size_t)(bcol + row) * N + kt + col, (const char*)Bs + ebyte);
    }
#pragma unroll
    for (int i = 0; i < 2; ++i) {
      int idx = i * 512 + tid;
      int e = idx * 4;
      int row = e >> 5, col = e & 31;
      float4 x = *(const float4*)(P + (size_t)(brow + row) * N + kt + col);
      ushort4 h = {f2bf(x.x), f2bf(x.y), f2bf(x.z), f2bf(x.w)};
      int inner = (col * 2) ^ (((row >> 1) & 3) << 4);
      *(ushort4*)((char*)As + row * 64 + inner) = h;
    }
    __syncthreads();

    bf16x8 a[4], b[4];
#pragma unroll
    for (int m = 0; m < 4; ++m) {
      int row = wr * 64 + m * 16 + fr;
      a[m] = *(const bf16x8*)((const char*)As + swz_byte(row, c0));
    }
#pragma unroll
    for (int n = 0; n < 4; ++n) {
      int row = wc * 64 + n * 16 + fr;
      b[n] = *(const bf16x8*)((const char*)Bs + swz_byte(row, c0));
    }
#pragma unroll
    for (int m = 0; m < 4; ++m)
#pragma unroll
      for (int n = 0; n < 4; ++n)
        acc[m][n] = __builtin_amdgcn_mfma_f32_16x16x32_bf16(a[m], b[n], acc[m][n], 0, 0, 0);
  }

  const int rr = (lane >> 4) * 4;
#pragma unroll
  for (int m = 0; m < 4; ++m)
#pragma unroll
    for (int n = 0; n < 4; ++n)
#pragma unroll
      for (int r = 0; r < 4; ++r) {
        int row = brow + wr * 64 + m * 16 + rr + r;
        int col = bcol + wc * 64 + n * 16 + fr;
        Out[(size_t)row * D + col] = acc[m][n][r];
      }
}

extern "C" void kernel_launch(void* const* d_in, const int* in_sizes, int n_in,
                              void* d_out, int out_size, void* d_ws, size_t ws_size,
                              hipStream_t stream) {
  const float* X = (const float*)d_in[0];
  float* out = (float*)d_out;
  float* attn = out + (size_t)N * D;        // second output: raw S, then softmaxed

  u16* Xh = (u16*)d_ws;                     // 16 MB
  u16* Xl = Xh + (size_t)N * D;             // 16 MB
  u16* XT = Xl + (size_t)N * D;             // 16 MB
  u16* Pb = XT + (size_t)N * D;             // 128 MB (optional)
  const bool usePb =
      ws_size >= ((size_t)N * D * 3 + (size_t)N * N) * sizeof(u16);

  k_split<<<(N * D / 4) / 256, 256, 0, stream>>>(X, Xh, Xl);
  k_transpose<<<dim3(D / 32, N / 32), 256, 0, stream>>>(Xh, XT);
  k_qkt<<<32 * 33 / 2, 512, 0, stream>>>(Xh, Xl, attn);
  if (usePb) {
    k_softmax<1><<<N, 256, 0, stream>>>(attn, Pb);
    k_pv<<<512, 256, 0, stream>>>(Pb, XT, out);
  } else {
    k_softmax<0><<<N, 256, 0, stream>>>(attn, nullptr);
    k_pv_f32<<<dim3(D / 256, N / 128), 512, 0, stream>>>(attn, XT, out);
  }
}

// Round 7
// 579.735 us; speedup vs baseline: 1.2581x; 1.2581x over previous
//
#include <hip/hip_runtime.h>

#define N 8192
#define D 1024

typedef short bf16x8 __attribute__((ext_vector_type(8)));
typedef float f32x4 __attribute__((ext_vector_type(4)));
typedef unsigned short u16;

#define WAITV(n) asm volatile("s_waitcnt vmcnt(" #n ")" ::: "memory")
#define BAR() __builtin_amdgcn_s_barrier()

__device__ __forceinline__ u16 f2bf(float f) {
  unsigned u = __float_as_uint(f);
  u += 0x7FFF + ((u >> 16) & 1);   // RNE to bf16
  return (u16)(u >> 16);
}
__device__ __forceinline__ float bf2f(u16 h) {
  return __uint_as_float(((unsigned)h) << 16);
}

__device__ __forceinline__ void gload_lds16(const void* g, const void* l) {
  __builtin_amdgcn_global_load_lds(
      (const __attribute__((address_space(1))) void*)g,
      (__attribute__((address_space(3))) void*)l, 16, 0, 0);
}

// Swizzled [rows][32] bf16 tile for LDS staging (pv): 64 B/row, 4x16B chunks.
__device__ __forceinline__ int swz_byte(int row, int logical_chunk) {
  return row * 64 + ((logical_chunk ^ ((row >> 1) & 3)) << 4);
}

// Fragment-major layout for X (hi/lo): tile (rt = r>>4, kt = k>>5) is 1 KiB at
// ((rt*32 + kt) << 10); within it lane = (r&15) + 16*((k>>3)&3) holds 16 B
// (8 bf16, e = k&7). Serves both MFMA A- and B-operands (identical gather).

// ---------------- K0: split X (fp32) into frag-major Hi/Lo bf16 ---------
__global__ __launch_bounds__(256) void k_split(const float* __restrict__ X,
                                               u16* __restrict__ hf,
                                               u16* __restrict__ lf) {
  int i = blockIdx.x * 256 + threadIdx.x;   // [0, N*D/8)
  int r = i >> 7;                           // D/8 = 128 chunks per row
  int kc = (i & 127) << 3;                  // col base, multiple of 8
  float4 x0 = *(const float4*)(X + (size_t)r * D + kc);
  float4 x1 = *(const float4*)(X + (size_t)r * D + kc + 4);
  float xs[8] = {x0.x, x0.y, x0.z, x0.w, x1.x, x1.y, x1.z, x1.w};
  u16 h[8], lo[8];
#pragma unroll
  for (int j = 0; j < 8; ++j) {
    h[j] = f2bf(xs[j]);
    lo[j] = f2bf(xs[j] - bf2f(h[j]));
  }
  size_t fb = ((size_t)(r >> 4) * 32 + (kc >> 5)) << 10;
  int lbyte = ((r & 15) + ((kc >> 3) & 3) * 16) * 16;
  *(int4*)((char*)hf + fb + lbyte) = *(int4*)h;
  *(int4*)((char*)lf + fb + lbyte) = *(int4*)lo;
}

// ---------------- K0b: transpose X (fp32) -> XT [D][N] bf16 row-major ---
__global__ __launch_bounds__(256) void k_xt(const float* __restrict__ X,
                                            u16* __restrict__ XT) {
  __shared__ u16 t[32][33];
  const int jt = blockIdx.y * 32, dt = blockIdx.x * 32;
  const int c = threadIdx.x & 31, rg = threadIdx.x >> 5;   // rg in 0..7
#pragma unroll
  for (int k = 0; k < 4; ++k) {
    int r = rg * 4 + k;
    t[r][c] = f2bf(X[(size_t)(jt + r) * D + dt + c]);
  }
  __syncthreads();
#pragma unroll
  for (int k = 0; k < 4; ++k) {
    int d = rg * 4 + k;
    XT[(size_t)(dt + d) * N + jt + c] = t[c][d];
  }
}

// ------- K1: S = X X^T, symmetric upper-tri 128x128 blocks --------------
// Fragment-direct: operands loaded global->VGPR from frag-major Xhf/Xlf
// (L2/L3-resident, 32 MB). NO LDS, NO barriers in the hot loop.
__global__ __launch_bounds__(256, 2) void k_qkt(const u16* __restrict__ Xhf,
                                                const u16* __restrict__ Xlf,
                                                float* __restrict__ S) {
  __shared__ float tbuf[128][64];   // epilogue transpose bounce only (32 KiB)
  const int tid = threadIdx.x, wid = tid >> 6, lane = tid & 63;

  // XCD chunk swizzle over 2080 blocks (2080 = 8 * 260, bijective)
  int o = blockIdx.x;
  int l = (o & 7) * 260 + (o >> 3);
  int t = l, bi = 0;
  while (t >= 64 - bi) { t -= 64 - bi; ++bi; }
  const int bj = bi + t;
  const int brow = bi * 128, bcol = bj * 128;

  const int wr = wid >> 1, wc = wid & 1;
  const int fr = lane & 15;

  // fragment base pointers: row-tile rt steps 32 KiB (32 k-tiles of 1 KiB)
  const char* pAh = (const char*)Xhf + ((size_t)(brow / 16 + wr * 4) << 15) + lane * 16;
  const char* pAl = (const char*)Xlf + ((size_t)(brow / 16 + wr * 4) << 15) + lane * 16;
  const char* pBh = (const char*)Xhf + ((size_t)(bcol / 16 + wc * 4) << 15) + lane * 16;
  const char* pBl = (const char*)Xlf + ((size_t)(bcol / 16 + wc * 4) << 15) + lane * 16;

  f32x4 acc[4][4] = {};

#define LOADF(P, kt) do {                                                  \
    _Pragma("unroll")                                                      \
    for (int m = 0; m < 4; ++m) {                                          \
      size_t off = ((size_t)m << 15) + ((size_t)(kt) << 10);               \
      P##ah[m] = *(const bf16x8*)(pAh + off);                              \
      P##al[m] = *(const bf16x8*)(pAl + off);                              \
      P##bh[m] = *(const bf16x8*)(pBh + off);                              \
      P##bl[m] = *(const bf16x8*)(pBl + off);                              \
    }                                                                      \
  } while (0)

#define FMAF(P) do {                                                       \
    _Pragma("unroll")                                                      \
    for (int m = 0; m < 4; ++m)                                            \
      _Pragma("unroll")                                                    \
      for (int n = 0; n < 4; ++n) {                                        \
        acc[m][n] = __builtin_amdgcn_mfma_f32_16x16x32_bf16(P##ah[m], P##bh[n], acc[m][n], 0, 0, 0); \
        acc[m][n] = __builtin_amdgcn_mfma_f32_16x16x32_bf16(P##ah[m], P##bl[n], acc[m][n], 0, 0, 0); \
        acc[m][n] = __builtin_amdgcn_mfma_f32_16x16x32_bf16(P##al[m], P##bh[n], acc[m][n], 0, 0, 0); \
      }                                                                    \
  } while (0)

  bf16x8 Aah[4], Aal[4], Abh[4], Abl[4];   // buffer A
  bf16x8 Bah[4], Bal[4], Bbh[4], Bbl[4];   // buffer B

  LOADF(A, 0);
  for (int kt = 0; kt < 30; kt += 2) {
    LOADF(B, kt + 1);
    FMAF(A);
    LOADF(A, kt + 2);
    FMAF(B);
  }
  LOADF(B, 31);
  FMAF(A);
  FMAF(B);

#undef LOADF
#undef FMAF

  const int rr = (lane >> 4) * 4;
  // direct tile write: S[brow..][bcol..]
#pragma unroll
  for (int m = 0; m < 4; ++m)
#pragma unroll
    for (int n = 0; n < 4; ++n)
#pragma unroll
      for (int r = 0; r < 4; ++r) {
        int row = brow + wr * 64 + m * 16 + rr + r;
        int col = bcol + wc * 64 + n * 16 + fr;
        S[(size_t)row * N + col] = acc[m][n][r];
      }

  // transposed tile write for off-diagonal blocks: S[bcol..][brow..]
  if (bi != bj) {
#pragma unroll
    for (int pass = 0; pass < 2; ++pass) {
      __syncthreads();
      if (wr == pass) {
#pragma unroll
        for (int m = 0; m < 4; ++m)
#pragma unroll
          for (int n = 0; n < 4; ++n) {
            f32x4 v = acc[m][n];
            int c = wc * 64 + n * 16 + fr;
            int inner = ((m * 16 + rr) * 4) ^ ((c & 15) << 4);
            *(f32x4*)((char*)&tbuf[c][0] + inner) = v;
          }
      }
      __syncthreads();
#pragma unroll
      for (int i = 0; i < 8; ++i) {
        int idx = i * 256 + tid;         // 2048 float4 = 128 cols x 16 quads
        int c = idx >> 4;                // 0..127
        int kq = idx & 15;               // 0..15
        int inner = (kq * 16) ^ ((c & 15) << 4);
        float4 v4 = *(const float4*)((const char*)&tbuf[c][0] + inner);
        *(float4*)&S[(size_t)(bcol + c) * N + brow + pass * 64 + kq * 4] = v4;
      }
    }
  }
}

// ---------------- K2: in-place row softmax (+ optional bf16 P copy) -----
template <int WRITE_PB>
__global__ __launch_bounds__(256) void k_softmax(float* __restrict__ S,
                                                 u16* __restrict__ Pb) {
  const int row = blockIdx.x;
  float* p = S + (size_t)row * N;
  const int tid = threadIdx.x;
  const int wid = tid >> 6, lane = tid & 63;
  __shared__ float red[4];

  float4 v[8];
  float m = -INFINITY;
#pragma unroll
  for (int i = 0; i < 8; ++i) {
    int idx = i * 256 + tid;              // float4 index within row
    float4 x = ((const float4*)p)[idx];
    if ((row >> 2) == idx) ((float*)&x)[row & 3] = -INFINITY;  // exclude diag
    v[i] = x;
    m = fmaxf(m, fmaxf(fmaxf(x.x, x.y), fmaxf(x.z, x.w)));
  }
#pragma unroll
  for (int off = 32; off > 0; off >>= 1) m = fmaxf(m, __shfl_xor(m, off));
  if (lane == 0) red[wid] = m;
  __syncthreads();
  m = fmaxf(fmaxf(red[0], red[1]), fmaxf(red[2], red[3]));

  float s = 0.f;
#pragma unroll
  for (int i = 0; i < 8; ++i) {
    float4 e;
    e.x = __expf(v[i].x - m);
    e.y = __expf(v[i].y - m);
    e.z = __expf(v[i].z - m);
    e.w = __expf(v[i].w - m);
    v[i] = e;
    s += e.x + e.y + e.z + e.w;
  }
#pragma unroll
  for (int off = 32; off > 0; off >>= 1) s += __shfl_xor(s, off);
  __syncthreads();                        // red[] reuse
  if (lane == 0) red[wid] = s;
  __syncthreads();
  s = red[0] + red[1] + red[2] + red[3];
  float inv = 1.0f / s;
#pragma unroll
  for (int i = 0; i < 8; ++i) {
    int idx = i * 256 + tid;
    float4 x = v[i];
    x.x *= inv; x.y *= inv; x.z *= inv; x.w *= inv;
    ((float4*)p)[idx] = x;
    if (WRITE_PB) {
      ushort4 h = {f2bf(x.x), f2bf(x.y), f2bf(x.z), f2bf(x.w)};
      ((ushort4*)(Pb + (size_t)row * N))[idx] = h;
    }
  }
}

// -------- K3: out = P @ X, bf16 Pb path. BM=BN=128, 256 thr -------------
// 4-deep global_load_lds pipeline, counted vmcnt, raw barriers (R6 proven).
__global__ __launch_bounds__(256) void k_pv(const u16* __restrict__ Pb,
                                            const u16* __restrict__ XT,
                                            float* __restrict__ Out) {
  __shared__ u16 As[4][128 * 32];   // 32 KiB
  __shared__ u16 Bs[4][128 * 32];   // 32 KiB
  const int tid = threadIdx.x, wid = tid >> 6, lane = tid & 63;

  // XCD chunk swizzle over 512 blocks (q=64, bijective)
  int o = blockIdx.x;
  int l = (o & 7) * 64 + (o >> 3);
  const int brow = (l >> 3) * 128;     // rows of P / out
  const int bcol = (l & 7) * 128;      // cols of out (d)

  const int wr = wid >> 1, wc = wid & 1;   // 2x2 waves, 64x64 each
  const int fr = lane & 15;
  const int c0 = lane >> 4;

  const bool isA = wid < 2;   // stage role: waves 0,1 -> A (Pb), 2,3 -> B (XT)

  f32x4 acc[4][4] = {};

#define PV_STAGE(kt, s) do {                                               \
    _Pragma("unroll")                                                      \
    for (int c = 0; c < 4; ++c) {                                          \
      int sub = (wid & 1) * 4 + c;           /* 0..7 within tile */        \
      int ebyte = sub * 1024 + lane * 16;                                  \
      int row = ebyte >> 6;                                                \
      int pc = (ebyte >> 4) & 3;                                           \
      int col = (pc ^ ((row >> 1) & 3)) * 8;                               \
      const u16* src = isA ? Pb + (size_t)(brow + row) * N + (kt) + col    \
                           : XT + (size_t)(bcol + row) * N + (kt) + col;   \
      gload_lds16(src, (const char*)(isA ? As[s] : Bs[s]) + ebyte);        \
    }                                                                      \
  } while (0)

#define PV_COMPUTE(s) do {                                                 \
    bf16x8 a[4], b[4];                                                     \
    _Pragma("unroll")                                                      \
    for (int m = 0; m < 4; ++m) {                                          \
      int row = wr * 64 + m * 16 + fr;                                     \
      a[m] = *(const bf16x8*)((const char*)As[s] + swz_byte(row, c0));     \
    }                                                                      \
    _Pragma("unroll")                                                      \
    for (int n = 0; n < 4; ++n) {                                          \
      int row = wc * 64 + n * 16 + fr;                                     \
      b[n] = *(const bf16x8*)((const char*)Bs[s] + swz_byte(row, c0));     \
    }                                                                      \
    _Pragma("unroll")                                                      \
    for (int m = 0; m < 4; ++m)                                            \
      _Pragma("unroll")                                                    \
      for (int n = 0; n < 4; ++n)                                          \
        acc[m][n] = __builtin_amdgcn_mfma_f32_16x16x32_bf16(a[m], b[n], acc[m][n], 0, 0, 0); \
  } while (0)

  PV_STAGE(0, 0);
  PV_STAGE(32, 1);
  PV_STAGE(64, 2);
  PV_STAGE(96, 3);
  int s = 0;
  for (int it = 0; it < 252; ++it) {
    WAITV(12);                   // tile it's 4 loads done; 12 in flight
    BAR();
    PV_COMPUTE(s);
    asm volatile("s_waitcnt lgkmcnt(0)" ::: "memory");
    BAR();
    PV_STAGE((it + 4) * 32, s);
    s = (s + 1) & 3;
  }
  WAITV(12); BAR(); PV_COMPUTE(s);
  asm volatile("s_waitcnt lgkmcnt(0)" ::: "memory"); BAR(); s = (s + 1) & 3;
  WAITV(8);  BAR(); PV_COMPUTE(s);
  asm volatile("s_waitcnt lgkmcnt(0)" ::: "memory"); BAR(); s = (s + 1) & 3;
  WAITV(4);  BAR(); PV_COMPUTE(s);
  asm volatile("s_waitcnt lgkmcnt(0)" ::: "memory"); BAR(); s = (s + 1) & 3;
  WAITV(0);  BAR(); PV_COMPUTE(s);

#undef PV_STAGE
#undef PV_COMPUTE

  const int rr = (lane >> 4) * 4;
#pragma unroll
  for (int m = 0; m < 4; ++m)
#pragma unroll
    for (int n = 0; n < 4; ++n)
#pragma unroll
      for (int r = 0; r < 4; ++r) {
        int row = brow + wr * 64 + m * 16 + rr + r;
        int col = bcol + wc * 64 + n * 16 + fr;
        Out[(size_t)row * D + col] = acc[m][n][r];
      }
}

// -------- K3 fallback: out = P @ X from fp32 P (no Pb workspace) --------
__global__ __launch_bounds__(512) void k_pv_f32(const float* __restrict__ P,
                                                const u16* __restrict__ XT,
                                                float* __restrict__ Out) {
  __shared__ u16 As[128 * 32];
  __shared__ u16 Bs[256 * 32];
  const int tid = threadIdx.x, wid = tid >> 6, lane = tid & 63;
  const int brow = blockIdx.y * 128;
  const int bcol = blockIdx.x * 256;
  const int wr = wid >> 2, wc = wid & 3;
  const int fr = lane & 15;
  const int c0 = lane >> 4;

  f32x4 acc[4][4] = {};

  for (int kt = 0; kt < N; kt += 32) {
    __syncthreads();
#pragma unroll
    for (int c = 0; c < 2; ++c) {
      int chunk = wid * 2 + c;
      int ebyte = chunk * 1024 + lane * 16;
      int row = ebyte >> 6;
      int pc = (ebyte >> 4) & 3;
      int col = (pc ^ ((row >> 1) & 3)) * 8;
      gload_lds16(XT + (size_t)(bcol + row) * N + kt + col, (const char*)Bs + ebyte);
    }
#pragma unroll
    for (int i = 0; i < 2; ++i) {
      int idx = i * 512 + tid;
      int e = idx * 4;
      int row = e >> 5, col = e & 31;
      float4 x = *(const float4*)(P + (size_t)(brow + row) * N + kt + col);
      ushort4 h = {f2bf(x.x), f2bf(x.y), f2bf(x.z), f2bf(x.w)};
      int inner = (col * 2) ^ (((row >> 1) & 3) << 4);
      *(ushort4*)((char*)As + row * 64 + inner) = h;
    }
    __syncthreads();

    bf16x8 a[4], b[4];
#pragma unroll
    for (int m = 0; m < 4; ++m) {
      int row = wr * 64 + m * 16 + fr;
      a[m] = *(const bf16x8*)((const char*)As + swz_byte(row, c0));
    }
#pragma unroll
    for (int n = 0; n < 4; ++n) {
      int row = wc * 64 + n * 16 + fr;
      b[n] = *(const bf16x8*)((const char*)Bs + swz_byte(row, c0));
    }
#pragma unroll
    for (int m = 0; m < 4; ++m)
#pragma unroll
      for (int n = 0; n < 4; ++n)
        acc[m][n] = __builtin_amdgcn_mfma_f32_16x16x32_bf16(a[m], b[n], acc[m][n], 0, 0, 0);
  }

  const int rr = (lane >> 4) * 4;
#pragma unroll
  for (int m = 0; m < 4; ++m)
#pragma unroll
    for (int n = 0; n < 4; ++n)
#pragma unroll
      for (int r = 0; r < 4; ++r) {
        int row = brow + wr * 64 + m * 16 + rr + r;
        int col = bcol + wc * 64 + n * 16 + fr;
        Out[(size_t)row * D + col] = acc[m][n][r];
      }
}

extern "C" void kernel_launch(void* const* d_in, const int* in_sizes, int n_in,
                              void* d_out, int out_size, void* d_ws, size_t ws_size,
                              hipStream_t stream) {
  const float* X = (const float*)d_in[0];
  float* out = (float*)d_out;
  float* attn = out + (size_t)N * D;        // second output: raw S, then softmaxed

  u16* Xhf = (u16*)d_ws;                    // 16 MB (frag-major hi)
  u16* Xlf = Xhf + (size_t)N * D;           // 16 MB (frag-major lo)
  u16* XT = Xlf + (size_t)N * D;            // 16 MB (row-major [D][N])
  u16* Pb = XT + (size_t)N * D;             // 128 MB (optional)
  const bool usePb =
      ws_size >= ((size_t)N * D * 3 + (size_t)N * N) * sizeof(u16);

  k_split<<<(N * D / 8) / 256, 256, 0, stream>>>(X, Xhf, Xlf);
  k_xt<<<dim3(D / 32, N / 32), 256, 0, stream>>>(X, XT);
  k_qkt<<<64 * 65 / 2, 256, 0, stream>>>(Xhf, Xlf, attn);
  if (usePb) {
    k_softmax<1><<<N, 256, 0, stream>>>(attn, Pb);
    k_pv<<<512, 256, 0, stream>>>(Pb, XT, out);
  } else {
    k_softmax<0><<<N, 256, 0, stream>>>(attn, nullptr);
    k_pv_f32<<<dim3(D / 256, N / 128), 512, 0, stream>>>(attn, XT, out);
  }
}